// Round 1
// baseline (1157.295 us; speedup 1.0000x reference)
//
#include <hip/hip_runtime.h>

// SSGC: h = alpha*x0 + (1-alpha)/K * sum_{k=1..K} (D^-1/2 A_hat D^-1/2)^k x0 ; out = h W^T + b
// N=50000, E=1.6M, D=128, K=16, alpha=0.05.
// R8: (1) deg histogram with 8 replicas -> 8x fewer per-line atomic collisions
//         (rank recombined via per-replica prefix, computed in-place over degR).
//     (2) single-block scan -> 3-dispatch parallel scan (part/mid/fin).
//     (3) agg restructured to 16-lane groups: one global_load_dwordx4 covers 4 edges
//         (1KB/instr), edge records broadcast via per-wave LDS ds_read_b64 instead of
//         2 shuffles/edge; butterfly (xor16,xor32) folds the 4 groups.
//     Keeps: bf16 feature rows, h RMW every 2 hops pairing x_k via the rounded self-row,
//     packed 8B edge records, f32 64x64-tile GEMM epilogue.

#define N_NODES 50000
#define N_EDGES 1600000
#define D 128
#define K_HOPS 16
#define ALPHA 0.05f
#define HCOEF ((1.0f - ALPHA) / (float)K_HOPS)
#define NREP 8
#define N_SBLK ((N_NODES + 255) / 256)   // 196 scan blocks

__device__ __forceinline__ unsigned int f2bf(float f) {
    unsigned int u = __float_as_uint(f);
    return (u + 0x7FFFu + ((u >> 16) & 1u)) >> 16;   // RNE
}
__device__ __forceinline__ unsigned int pack_bf2(float x, float y) {
    return f2bf(x) | (f2bf(y) << 16);
}
__device__ __forceinline__ float bf_lo(unsigned int w) { return __uint_as_float(w << 16); }
__device__ __forceinline__ float bf_hi(unsigned int w) { return __uint_as_float(w & 0xFFFF0000u); }

// Replicated in-degree histogram: replica = blockIdx & 7 spreads the 512-atomics/line
// hotspot over 8x the lines. rank[i] is the within-(replica,dst) arrival order.
__global__ void deg_kernel(const int* __restrict__ dst, int* __restrict__ degR,
                           int* __restrict__ rank, int e) {
    int i = blockIdx.x * 256 + threadIdx.x;
    if (i < e) {
        int rep = blockIdx.x & (NREP - 1);
        rank[i] = atomicAdd(&degR[rep * N_NODES + dst[i]], 1);
    }
}

// Fold replicas: degR[r][i] becomes the exclusive prefix over replicas (pref),
// deg[i] = total. Also computes dinv/selfw (folds old dinv_kernel).
__global__ void combine_kernel(int* __restrict__ degR, int* __restrict__ deg,
                               float* __restrict__ dinv, float* __restrict__ selfw, int n) {
    int i = blockIdx.x * 256 + threadIdx.x;
    if (i < n) {
        int run = 0;
        #pragma unroll
        for (int r = 0; r < NREP; ++r) {
            int v = degR[r * N_NODES + i];
            degR[r * N_NODES + i] = run;   // in-place: degR becomes pref
            run += v;
        }
        deg[i] = run;
        float di = rsqrtf((float)(run + 1));
        dinv[i] = di;
        selfw[i] = di * di;
    }
}

// 256-thread block exclusive scan (shfl wave scans + 4-wave LDS combine).
__device__ __forceinline__ int block_scan_excl(int v) {
    __shared__ int ws[4];
    int tid = threadIdx.x, lane = tid & 63, wid = tid >> 6;
    int s = v;
    #pragma unroll
    for (int off = 1; off < 64; off <<= 1) {
        int t = __shfl_up(s, off, 64);
        if (lane >= off) s += t;
    }
    if (lane == 63) ws[wid] = s;
    __syncthreads();
    int woff = 0;
    #pragma unroll
    for (int w = 0; w < 3; ++w)
        if (w < wid) woff += ws[w];
    return woff + s - v;
}

__global__ void scan_part(const int* __restrict__ deg, int* __restrict__ part, int n) {
    int i = blockIdx.x * 256 + threadIdx.x;
    int v = (i < n) ? deg[i] : 0;
    #pragma unroll
    for (int off = 1; off < 64; off <<= 1) v += __shfl_xor(v, off, 64);
    __shared__ int ws[4];
    if ((threadIdx.x & 63) == 0) ws[threadIdx.x >> 6] = v;
    __syncthreads();
    if (threadIdx.x == 0) part[blockIdx.x] = ws[0] + ws[1] + ws[2] + ws[3];
}

__global__ void scan_mid(int* __restrict__ part, int nb) {
    int tid = threadIdx.x;
    int v = (tid < nb) ? part[tid] : 0;
    int e = block_scan_excl(v);
    if (tid < nb) part[tid] = e;
}

__global__ void scan_fin(const int* __restrict__ deg, const int* __restrict__ part,
                         int* __restrict__ row_start, int n) {
    int i = blockIdx.x * 256 + threadIdx.x;
    int v = (i < n) ? deg[i] : 0;
    int e = block_scan_excl(v) + part[blockIdx.x];
    if (i < n) row_start[i] = e;
    if (i == n - 1) row_start[n] = e + v;
}

// One 8B scattered store per edge: record = (src, bitcast(norm weight)).
// pos = row_start[d] + replica prefix + within-replica rank. Replica mapping must
// match deg_kernel exactly (same block size/grid => blockIdx & 7).
__global__ void scatter_kernel(const int* __restrict__ src, const int* __restrict__ dst,
                               const int* __restrict__ rank, const int* __restrict__ row_start,
                               const int* __restrict__ pref, int2* __restrict__ csr,
                               const float* __restrict__ dinv, int e) {
    int i = blockIdx.x * 256 + threadIdx.x;
    if (i < e) {
        int rep = blockIdx.x & (NREP - 1);
        int d = dst[i];
        int s = src[i];
        int pos = row_start[d] + pref[rep * N_NODES + d] + rank[i];
        csr[pos] = make_int2(s, __float_as_int(dinv[d] * dinv[s]));
    }
}

// x0 -> packed bf16 x; h = alpha * x0 (exact f32).
__global__ void init_kernel(const float2* __restrict__ x0, unsigned int* __restrict__ xb,
                            float2* __restrict__ h, int n2) {
    int i = blockIdx.x * blockDim.x + threadIdx.x;
    if (i < n2) {
        float2 v = x0[i];
        xb[i] = pack_bf2(v.x, v.y);
        h[i] = make_float2(ALPHA * v.x, ALPHA * v.y);
    }
}

#define ACC8(W, G)                                                          \
    acc[0] += (W) * bf_lo((G).x); acc[1] += (W) * bf_hi((G).x);             \
    acc[2] += (W) * bf_lo((G).y); acc[3] += (W) * bf_hi((G).y);             \
    acc[4] += (W) * bf_lo((G).z); acc[5] += (W) * bf_hi((G).z);             \
    acc[6] += (W) * bf_lo((G).w); acc[7] += (W) * bf_hi((G).w);

// NW*4 edges per step: group g (lane>>4) handles edge j+4q+g, lane's 16B covers
// features sub*8..sub*8+7. One dwordx4 per 4 edges; records via ds_read_b64.
#define GATHER_STEP(NW)                                                     \
    {                                                                       \
        int2 er[NW];                                                        \
        uint4 gr[NW];                                                       \
        _Pragma("unroll") for (int q = 0; q < (NW); ++q)                    \
            er[q] = srec[wid][j + 4 * q + grp];                             \
        _Pragma("unroll") for (int q = 0; q < (NW); ++q)                    \
            gr[q] = xb4[(er[q].x << 4) + sub];                              \
        _Pragma("unroll") for (int q = 0; q < (NW); ++q) {                  \
            float w = __int_as_float(er[q].y);                              \
            ACC8(w, gr[q]);                                                 \
        }                                                                   \
        j += 4 * (NW);                                                      \
    }

// One wave per node. 4 x 16-lane groups process 4 edges per load instruction.
// Tail groups are masked with w=0 (their clamped record reads valid memory).
// Butterfly (xor16, xor32) folds group partials; grp 0 adds the self term,
// packs bf16, and does the h RMW every 2nd hop (x_k rounded + x_{k+1} fresh).
__global__ __launch_bounds__(256) void agg_kernel(
    const uint4* __restrict__ xb4, uint4* __restrict__ yb4,
    float4* __restrict__ h4, const float* __restrict__ selfw,
    const int* __restrict__ row_start, const int2* __restrict__ csr, int update_h) {
    __shared__ int2 srec[4][64];
    int wid = threadIdx.x >> 6;
    int lane = threadIdx.x & 63;
    int grp = lane >> 4, sub = lane & 15;
    int node = blockIdx.x * 4 + wid;
    if (node >= N_NODES) return;

    int r0 = row_start[node];
    int r1 = row_start[node + 1];
    int dg = r1 - r0;

    float acc[8] = {0.f, 0.f, 0.f, 0.f, 0.f, 0.f, 0.f, 0.f};

    for (int base = 0; base < dg; base += 64) {
        int cnt = dg - base;
        if (cnt > 64) cnt = 64;
        int idx = r0 + base + lane;
        if (idx >= r1) idx = r1 - 1;           // clamped slots only consumed with w=0
        srec[wid][lane] = csr[idx];            // per-wave region: no barrier needed

        int j = 0;
        while (j + 32 <= cnt) GATHER_STEP(8);
        while (j + 16 <= cnt) GATHER_STEP(4);
        if (j + 8 <= cnt) GATHER_STEP(2);
        while (j < cnt) {                      // masked tail, <=2 iterations
            int2 er = srec[wid][j + grp];
            uint4 gr = xb4[(er.x << 4) + sub];
            float w = (j + grp < cnt) ? __int_as_float(er.y) : 0.f;
            ACC8(w, gr);
            j += 4;
        }
    }

    #pragma unroll
    for (int q = 0; q < 8; ++q) {
        acc[q] += __shfl_xor(acc[q], 16, 64);
        acc[q] += __shfl_xor(acc[q], 32, 64);
    }

    if (grp == 0) {
        int o = (node << 4) + sub;
        uint4 vw = xb4[o];
        float sw = selfw[node];
        float xs[8] = {bf_lo(vw.x), bf_hi(vw.x), bf_lo(vw.y), bf_hi(vw.y),
                       bf_lo(vw.z), bf_hi(vw.z), bf_lo(vw.w), bf_hi(vw.w)};
        #pragma unroll
        for (int q = 0; q < 8; ++q) acc[q] += sw * xs[q];
        uint4 ov;
        ov.x = pack_bf2(acc[0], acc[1]);
        ov.y = pack_bf2(acc[2], acc[3]);
        ov.z = pack_bf2(acc[4], acc[5]);
        ov.w = pack_bf2(acc[6], acc[7]);
        yb4[o] = ov;                           // bf16 state for next hop
        if (update_h) {
            int ho = (node << 5) + (sub << 1);
            float4 h0 = h4[ho], h1 = h4[ho + 1];
            h0.x += HCOEF * (xs[0] + acc[0]); h0.y += HCOEF * (xs[1] + acc[1]);
            h0.z += HCOEF * (xs[2] + acc[2]); h0.w += HCOEF * (xs[3] + acc[3]);
            h1.x += HCOEF * (xs[4] + acc[4]); h1.y += HCOEF * (xs[5] + acc[5]);
            h1.z += HCOEF * (xs[6] + acc[6]); h1.w += HCOEF * (xs[7] + acc[7]);
            h4[ho] = h0; h4[ho + 1] = h1;
        }
    }
}

// out[r][c] = sum_k h[r][k]*W[c][k] + bias[c]. h and out are DIFFERENT buffers.
// Block: 64 rows x 64 cols, 256 threads, 4x4 acc/thread. k-major LDS tiles.
__global__ __launch_bounds__(256) void gemm_kernel(
    const float* __restrict__ h, const float* __restrict__ w,
    const float* __restrict__ bias, float* __restrict__ out) {
    __shared__ float sAT[128][64];   // [k][row]
    __shared__ float sBT[128][64];   // [k][col]
    int tid = threadIdx.x;
    int row0 = blockIdx.x * 64;
    int col0 = blockIdx.y * 64;

    for (int idx = tid; idx < 64 * 32; idx += 256) {
        int r = idx & 63, kq = idx >> 6;
        float4 v;
        if (row0 + r < N_NODES)
            v = *(const float4*)&h[(size_t)(row0 + r) * D + kq * 4];
        else
            v = make_float4(0.f, 0.f, 0.f, 0.f);
        sAT[kq * 4 + 0][r] = v.x;
        sAT[kq * 4 + 1][r] = v.y;
        sAT[kq * 4 + 2][r] = v.z;
        sAT[kq * 4 + 3][r] = v.w;
    }
    for (int idx = tid; idx < 64 * 32; idx += 256) {
        int c = idx & 63, kq = idx >> 6;
        float4 v = *(const float4*)&w[(size_t)(col0 + c) * D + kq * 4];
        sBT[kq * 4 + 0][c] = v.x;
        sBT[kq * 4 + 1][c] = v.y;
        sBT[kq * 4 + 2][c] = v.z;
        sBT[kq * 4 + 3][c] = v.w;
    }
    __syncthreads();

    int cg = tid & 15;    // cols cg*4..+4
    int rg = tid >> 4;    // rows rg*4..+4
    float acc[4][4] = {};
    #pragma unroll 2
    for (int k = 0; k < 128; ++k) {
        float4 a = *(const float4*)&sAT[k][rg * 4];
        float4 b = *(const float4*)&sBT[k][cg * 4];
        acc[0][0] += a.x * b.x; acc[0][1] += a.x * b.y; acc[0][2] += a.x * b.z; acc[0][3] += a.x * b.w;
        acc[1][0] += a.y * b.x; acc[1][1] += a.y * b.y; acc[1][2] += a.y * b.z; acc[1][3] += a.y * b.w;
        acc[2][0] += a.z * b.x; acc[2][1] += a.z * b.y; acc[2][2] += a.z * b.z; acc[2][3] += a.z * b.w;
        acc[3][0] += a.w * b.x; acc[3][1] += a.w * b.y; acc[3][2] += a.w * b.z; acc[3][3] += a.w * b.w;
    }

    float4 bv = *(const float4*)&bias[col0 + cg * 4];
    #pragma unroll
    for (int i = 0; i < 4; ++i) {
        int r = row0 + rg * 4 + i;
        if (r < N_NODES) {
            float4 ov = make_float4(acc[i][0] + bv.x, acc[i][1] + bv.y,
                                    acc[i][2] + bv.z, acc[i][3] + bv.w);
            *(float4*)&out[(size_t)r * D + col0 + cg * 4] = ov;
        }
    }
}

extern "C" void kernel_launch(void* const* d_in, const int* in_sizes, int n_in,
                              void* d_out, int out_size, void* d_ws, size_t ws_size,
                              hipStream_t stream) {
    const float* node_emb = (const float*)d_in[0];
    const int*   edge     = (const int*)d_in[1];   // [2,E]: row 0 = src, row 1 = dst
    const float* weight   = (const float*)d_in[2]; // [D_OUT, D_IN] row-major
    const float* bias     = (const float*)d_in[3];
    float* out = (float*)d_out;

    char* ws = (char*)d_ws;
    float*        hbuf = (float*)ws;        ws += (size_t)N_NODES * D * sizeof(float);
    unsigned int* xb0  = (unsigned int*)ws; ws += (size_t)N_NODES * 64 * sizeof(unsigned int);
    unsigned int* xb1  = (unsigned int*)ws; ws += (size_t)N_NODES * 64 * sizeof(unsigned int);
    int2*  csr      = (int2*)ws;  ws += (size_t)N_EDGES * sizeof(int2);
    int*   rank     = (int*)ws;   ws += (size_t)N_EDGES * sizeof(int);
    int*   degR     = (int*)ws;   ws += (size_t)NREP * N_NODES * sizeof(int);  // -> pref
    int*   deg      = (int*)ws;   ws += (size_t)N_NODES * sizeof(int);
    int*   row_start= (int*)ws;   ws += (size_t)(N_NODES + 16) * sizeof(int);
    float* dinv     = (float*)ws; ws += (size_t)N_NODES * sizeof(float);
    float* selfw    = (float*)ws; ws += (size_t)N_NODES * sizeof(float);
    int*   part     = (int*)ws;   ws += 256 * sizeof(int);

    const int* srcp = edge;
    const int* dstp = edge + N_EDGES;

    hipMemsetAsync(degR, 0, (size_t)NREP * N_NODES * sizeof(int), stream);

    deg_kernel<<<(N_EDGES + 255) / 256, 256, 0, stream>>>(dstp, degR, rank, N_EDGES);
    combine_kernel<<<(N_NODES + 255) / 256, 256, 0, stream>>>(degR, deg, dinv, selfw, N_NODES);
    scan_part<<<N_SBLK, 256, 0, stream>>>(deg, part, N_NODES);
    scan_mid<<<1, 256, 0, stream>>>(part, N_SBLK);
    scan_fin<<<N_SBLK, 256, 0, stream>>>(deg, part, row_start, N_NODES);
    scatter_kernel<<<(N_EDGES + 255) / 256, 256, 0, stream>>>(srcp, dstp, rank, row_start,
                                                              degR, csr, dinv, N_EDGES);

    int n2 = N_NODES * D / 2;
    init_kernel<<<(n2 + 255) / 256, 256, 0, stream>>>((const float2*)node_emb, xb0,
                                                      (float2*)hbuf, n2);

    unsigned int* cur = xb0;
    unsigned int* nxt = xb1;
    for (int k = 0; k < K_HOPS; ++k) {
        agg_kernel<<<(N_NODES + 3) / 4, 256, 0, stream>>>(
            (const uint4*)cur, (uint4*)nxt, (float4*)hbuf, selfw, row_start, csr, k & 1);
        unsigned int* tmp = cur; cur = nxt; nxt = tmp;
    }

    // Out-of-place GEMM: reads hbuf (f32), writes d_out.
    dim3 ggrid((N_NODES + 63) / 64, 2);
    gemm_kernel<<<ggrid, 256, 0, stream>>>(hbuf, weight, bias, out);
}

// Round 2
// 1071.749 us; speedup vs baseline: 1.0798x; 1.0798x over previous
//
#include <hip/hip_runtime.h>

// SSGC: h = alpha*x0 + (1-alpha)/K * sum_{k=1..K} (D^-1/2 A_hat D^-1/2)^k x0 ; out = h W^T + b
// N=50000, E=1.6M, D=128, K=16, alpha=0.05.
// R9: (1) deg/scatter were latency-bound at MLP=1/thread (measured 96M atomics/s/CU ==
//         32 waves / ~800cy RMW latency). deg now does 8 edges/thread (int4 loads,
//         8 independent atomics in flight); scatter does 4 edges/thread.
//         Replica id derived from EDGE INDEX ((i>>11)&7) so both kernels agree.
//     (2) agg reverted to the R7 shuffle-broadcast form: the R8 16-lane-group LDS
//         restructure kept per-edge memory requests identical (one 256B fetch/edge)
//         and only cut instruction issue (never the bound) while adding LDS+butterfly
//         overhead (~+4us/hop). R7 form is the known-best memory-bound schedule.
//     Keeps: replicated histogram (8 reps), 3-dispatch parallel scan, bf16 feature
//     rows, h RMW every 2 hops via the rounded self-row, packed 8B edge records,
//     f32 64x64-tile GEMM epilogue.

#define N_NODES 50000
#define N_EDGES 1600000
#define D 128
#define K_HOPS 16
#define ALPHA 0.05f
#define HCOEF ((1.0f - ALPHA) / (float)K_HOPS)
#define NREP 8
#define N_SBLK ((N_NODES + 255) / 256)   // 196 scan blocks

// deg: 8 edges/thread -> replica of edge i is ((i >> 11) & 7) (2048 edges per block).
#define DEG_IPT 8
#define REP_OF(i) (((i) >> 11) & (NREP - 1))

__device__ __forceinline__ unsigned int f2bf(float f) {
    unsigned int u = __float_as_uint(f);
    return (u + 0x7FFFu + ((u >> 16) & 1u)) >> 16;   // RNE
}
__device__ __forceinline__ unsigned int pack_bf2(float x, float y) {
    return f2bf(x) | (f2bf(y) << 16);
}
__device__ __forceinline__ float bf_lo(unsigned int w) { return __uint_as_float(w << 16); }
__device__ __forceinline__ float bf_hi(unsigned int w) { return __uint_as_float(w & 0xFFFF0000u); }

// Replicated in-degree histogram, 8 edges per thread (two int4 loads).
// 8 independent atomics in flight per lane breaks the MLP=1 latency wall.
__global__ void deg_kernel(const int* __restrict__ dst, int* __restrict__ degR,
                           int* __restrict__ rank, int e) {
    int gid = blockIdx.x * 256 + threadIdx.x;
    int i0 = gid * DEG_IPT;
    if (i0 >= e) return;
    int rep = REP_OF(i0);                    // all 8 edges share one replica
    int* base = degR + rep * N_NODES;
    int4 d0 = *(const int4*)&dst[i0];
    int4 d1 = *(const int4*)&dst[i0 + 4];
    int r[8];
    r[0] = atomicAdd(&base[d0.x], 1);
    r[1] = atomicAdd(&base[d0.y], 1);
    r[2] = atomicAdd(&base[d0.z], 1);
    r[3] = atomicAdd(&base[d0.w], 1);
    r[4] = atomicAdd(&base[d1.x], 1);
    r[5] = atomicAdd(&base[d1.y], 1);
    r[6] = atomicAdd(&base[d1.z], 1);
    r[7] = atomicAdd(&base[d1.w], 1);
    *(int4*)&rank[i0]     = make_int4(r[0], r[1], r[2], r[3]);
    *(int4*)&rank[i0 + 4] = make_int4(r[4], r[5], r[6], r[7]);
}

// Fold replicas: degR[r][i] becomes the exclusive prefix over replicas (pref),
// deg[i] = total. Also computes dinv/selfw.
__global__ void combine_kernel(int* __restrict__ degR, int* __restrict__ deg,
                               float* __restrict__ dinv, float* __restrict__ selfw, int n) {
    int i = blockIdx.x * 256 + threadIdx.x;
    if (i < n) {
        int run = 0;
        #pragma unroll
        for (int r = 0; r < NREP; ++r) {
            int v = degR[r * N_NODES + i];
            degR[r * N_NODES + i] = run;   // in-place: degR becomes pref
            run += v;
        }
        deg[i] = run;
        float di = rsqrtf((float)(run + 1));
        dinv[i] = di;
        selfw[i] = di * di;
    }
}

// 256-thread block exclusive scan (shfl wave scans + 4-wave LDS combine).
__device__ __forceinline__ int block_scan_excl(int v) {
    __shared__ int ws[4];
    int tid = threadIdx.x, lane = tid & 63, wid = tid >> 6;
    int s = v;
    #pragma unroll
    for (int off = 1; off < 64; off <<= 1) {
        int t = __shfl_up(s, off, 64);
        if (lane >= off) s += t;
    }
    if (lane == 63) ws[wid] = s;
    __syncthreads();
    int woff = 0;
    #pragma unroll
    for (int w = 0; w < 3; ++w)
        if (w < wid) woff += ws[w];
    return woff + s - v;
}

__global__ void scan_part(const int* __restrict__ deg, int* __restrict__ part, int n) {
    int i = blockIdx.x * 256 + threadIdx.x;
    int v = (i < n) ? deg[i] : 0;
    #pragma unroll
    for (int off = 1; off < 64; off <<= 1) v += __shfl_xor(v, off, 64);
    __shared__ int ws[4];
    if ((threadIdx.x & 63) == 0) ws[threadIdx.x >> 6] = v;
    __syncthreads();
    if (threadIdx.x == 0) part[blockIdx.x] = ws[0] + ws[1] + ws[2] + ws[3];
}

__global__ void scan_mid(int* __restrict__ part, int nb) {
    int tid = threadIdx.x;
    int v = (tid < nb) ? part[tid] : 0;
    int e = block_scan_excl(v);
    if (tid < nb) part[tid] = e;
}

__global__ void scan_fin(const int* __restrict__ deg, const int* __restrict__ part,
                         int* __restrict__ row_start, int n) {
    int i = blockIdx.x * 256 + threadIdx.x;
    int v = (i < n) ? deg[i] : 0;
    int e = block_scan_excl(v) + part[blockIdx.x];
    if (i < n) row_start[i] = e;
    if (i == n - 1) row_start[n] = e + v;
}

// One 8B scattered store per edge: record = (src, bitcast(norm weight)).
// 4 edges/thread for memory-level parallelism on the random 4B gathers.
// pos = row_start[d] + replica prefix (REP_OF must match deg_kernel's mapping).
__global__ void scatter_kernel(const int* __restrict__ src, const int* __restrict__ dst,
                               const int* __restrict__ rank, const int* __restrict__ row_start,
                               const int* __restrict__ pref, int2* __restrict__ csr,
                               const float* __restrict__ dinv, int e) {
    int gid = blockIdx.x * 256 + threadIdx.x;
    int i0 = gid * 4;
    if (i0 >= e) return;
    int4 dv = *(const int4*)&dst[i0];
    int4 sv = *(const int4*)&src[i0];
    int4 rv = *(const int4*)&rank[i0];
    int d[4] = {dv.x, dv.y, dv.z, dv.w};
    int s[4] = {sv.x, sv.y, sv.z, sv.w};
    int r[4] = {rv.x, rv.y, rv.z, rv.w};
    int pos[4];
    float w[4];
    #pragma unroll
    for (int q = 0; q < 4; ++q) {
        int rep = REP_OF(i0 + q);
        pos[q] = row_start[d[q]] + pref[rep * N_NODES + d[q]] + r[q];
        w[q] = dinv[d[q]] * dinv[s[q]];
    }
    #pragma unroll
    for (int q = 0; q < 4; ++q)
        csr[pos[q]] = make_int2(s[q], __float_as_int(w[q]));
}

// x0 -> packed bf16 x; h = alpha * x0 (exact f32).
__global__ void init_kernel(const float2* __restrict__ x0, unsigned int* __restrict__ xb,
                            float2* __restrict__ h, int n2) {
    int i = blockIdx.x * blockDim.x + threadIdx.x;
    if (i < n2) {
        float2 v = x0[i];
        xb[i] = pack_bf2(v.x, v.y);
        h[i] = make_float2(ALPHA * v.x, ALPHA * v.y);
    }
}

#define GATHER_BLOCK(W)                                                         \
    {                                                                           \
        unsigned int g[W];                                                      \
        float wv[W];                                                            \
        _Pragma("unroll") for (int q = 0; q < W; ++q) {                         \
            int s = __shfl(rec.x, j + q);                                       \
            wv[q] = __int_as_float(__shfl(rec.y, j + q));                       \
            g[q] = xb[(size_t)s * 64 + lane];                                   \
        }                                                                       \
        _Pragma("unroll") for (int q = 0; q < W; ++q) {                         \
            accx += wv[q] * bf_lo(g[q]);                                        \
            accy += wv[q] * bf_hi(g[q]);                                        \
        }                                                                       \
        j += W;                                                                 \
    }

// One wave (64 lanes) per node; lane owns features [2*lane, 2*lane+1] (one packed dword).
// Edge records loaded 64-at-a-time coalesced, broadcast with shfl; stepped unroll 16/8/4.
// update_h: h += c*(x_k + x_{k+1}) using the rounded self-row (x_k) + fresh acc (x_{k+1}).
__global__ __launch_bounds__(256) void agg_kernel(
    const unsigned int* __restrict__ xb, unsigned int* __restrict__ yb,
    float2* __restrict__ h2, const float* __restrict__ selfw,
    const int* __restrict__ row_start, const int2* __restrict__ csr, int update_h) {
    int wid = threadIdx.x >> 6;
    int lane = threadIdx.x & 63;
    int node = blockIdx.x * 4 + wid;
    if (node >= N_NODES) return;

    int r0 = row_start[node];
    int r1 = row_start[node + 1];
    int deg = r1 - r0;
    size_t o = (size_t)node * 64 + lane;

    unsigned int vw = xb[o];
    float sw = selfw[node];
    float accx = sw * bf_lo(vw), accy = sw * bf_hi(vw);

    for (int base = 0; base < deg; base += 64) {
        int cnt = deg - base;
        if (cnt > 64) cnt = 64;
        int idx = r0 + base + lane;
        if (idx >= r1) idx = r1 - 1;           // clamped lanes are never shfl-read
        int2 rec = csr[idx];                   // one coalesced dwordx2 per wave

        int j = 0;
        while (j + 16 <= cnt) GATHER_BLOCK(16);
        if (j + 8 <= cnt) GATHER_BLOCK(8);
        if (j + 4 <= cnt) GATHER_BLOCK(4);
        for (; j < cnt; ++j) {
            int s = __shfl(rec.x, j);
            float w = __int_as_float(__shfl(rec.y, j));
            unsigned int gw = xb[(size_t)s * 64 + lane];
            accx += w * bf_lo(gw);
            accy += w * bf_hi(gw);
        }
    }

    yb[o] = pack_bf2(accx, accy);              // bf16 state for next hop
    if (update_h) {
        float2 hv = h2[o];
        hv.x += HCOEF * (bf_lo(vw) + accx);    // x_k (rounded) + x_{k+1} (pre-round)
        hv.y += HCOEF * (bf_hi(vw) + accy);
        h2[o] = hv;
    }
}

// out[r][c] = sum_k h[r][k]*W[c][k] + bias[c]. h and out are DIFFERENT buffers.
// Block: 64 rows x 64 cols, 256 threads, 4x4 acc/thread. k-major LDS tiles.
__global__ __launch_bounds__(256) void gemm_kernel(
    const float* __restrict__ h, const float* __restrict__ w,
    const float* __restrict__ bias, float* __restrict__ out) {
    __shared__ float sAT[128][64];   // [k][row]
    __shared__ float sBT[128][64];   // [k][col]
    int tid = threadIdx.x;
    int row0 = blockIdx.x * 64;
    int col0 = blockIdx.y * 64;

    for (int idx = tid; idx < 64 * 32; idx += 256) {
        int r = idx & 63, kq = idx >> 6;
        float4 v;
        if (row0 + r < N_NODES)
            v = *(const float4*)&h[(size_t)(row0 + r) * D + kq * 4];
        else
            v = make_float4(0.f, 0.f, 0.f, 0.f);
        sAT[kq * 4 + 0][r] = v.x;
        sAT[kq * 4 + 1][r] = v.y;
        sAT[kq * 4 + 2][r] = v.z;
        sAT[kq * 4 + 3][r] = v.w;
    }
    for (int idx = tid; idx < 64 * 32; idx += 256) {
        int c = idx & 63, kq = idx >> 6;
        float4 v = *(const float4*)&w[(size_t)(col0 + c) * D + kq * 4];
        sBT[kq * 4 + 0][c] = v.x;
        sBT[kq * 4 + 1][c] = v.y;
        sBT[kq * 4 + 2][c] = v.z;
        sBT[kq * 4 + 3][c] = v.w;
    }
    __syncthreads();

    int cg = tid & 15;    // cols cg*4..+4
    int rg = tid >> 4;    // rows rg*4..+4
    float acc[4][4] = {};
    #pragma unroll 2
    for (int k = 0; k < 128; ++k) {
        float4 a = *(const float4*)&sAT[k][rg * 4];
        float4 b = *(const float4*)&sBT[k][cg * 4];
        acc[0][0] += a.x * b.x; acc[0][1] += a.x * b.y; acc[0][2] += a.x * b.z; acc[0][3] += a.x * b.w;
        acc[1][0] += a.y * b.x; acc[1][1] += a.y * b.y; acc[1][2] += a.y * b.z; acc[1][3] += a.y * b.w;
        acc[2][0] += a.z * b.x; acc[2][1] += a.z * b.y; acc[2][2] += a.z * b.z; acc[2][3] += a.z * b.w;
        acc[3][0] += a.w * b.x; acc[3][1] += a.w * b.y; acc[3][2] += a.w * b.z; acc[3][3] += a.w * b.w;
    }

    float4 bv = *(const float4*)&bias[col0 + cg * 4];
    #pragma unroll
    for (int i = 0; i < 4; ++i) {
        int r = row0 + rg * 4 + i;
        if (r < N_NODES) {
            float4 ov = make_float4(acc[i][0] + bv.x, acc[i][1] + bv.y,
                                    acc[i][2] + bv.z, acc[i][3] + bv.w);
            *(float4*)&out[(size_t)r * D + col0 + cg * 4] = ov;
        }
    }
}

extern "C" void kernel_launch(void* const* d_in, const int* in_sizes, int n_in,
                              void* d_out, int out_size, void* d_ws, size_t ws_size,
                              hipStream_t stream) {
    const float* node_emb = (const float*)d_in[0];
    const int*   edge     = (const int*)d_in[1];   // [2,E]: row 0 = src, row 1 = dst
    const float* weight   = (const float*)d_in[2]; // [D_OUT, D_IN] row-major
    const float* bias     = (const float*)d_in[3];
    float* out = (float*)d_out;

    char* ws = (char*)d_ws;
    float*        hbuf = (float*)ws;        ws += (size_t)N_NODES * D * sizeof(float);
    unsigned int* xb0  = (unsigned int*)ws; ws += (size_t)N_NODES * 64 * sizeof(unsigned int);
    unsigned int* xb1  = (unsigned int*)ws; ws += (size_t)N_NODES * 64 * sizeof(unsigned int);
    int2*  csr      = (int2*)ws;  ws += (size_t)N_EDGES * sizeof(int2);
    int*   rank     = (int*)ws;   ws += (size_t)N_EDGES * sizeof(int);
    int*   degR     = (int*)ws;   ws += (size_t)NREP * N_NODES * sizeof(int);  // -> pref
    int*   deg      = (int*)ws;   ws += (size_t)N_NODES * sizeof(int);
    int*   row_start= (int*)ws;   ws += (size_t)(N_NODES + 16) * sizeof(int);
    float* dinv     = (float*)ws; ws += (size_t)N_NODES * sizeof(float);
    float* selfw    = (float*)ws; ws += (size_t)N_NODES * sizeof(float);
    int*   part     = (int*)ws;   ws += 256 * sizeof(int);

    const int* srcp = edge;
    const int* dstp = edge + N_EDGES;

    hipMemsetAsync(degR, 0, (size_t)NREP * N_NODES * sizeof(int), stream);

    int deg_threads = N_EDGES / DEG_IPT;                       // 200000, exact
    deg_kernel<<<(deg_threads + 255) / 256, 256, 0, stream>>>(dstp, degR, rank, N_EDGES);
    combine_kernel<<<(N_NODES + 255) / 256, 256, 0, stream>>>(degR, deg, dinv, selfw, N_NODES);
    scan_part<<<N_SBLK, 256, 0, stream>>>(deg, part, N_NODES);
    scan_mid<<<1, 256, 0, stream>>>(part, N_SBLK);
    scan_fin<<<N_SBLK, 256, 0, stream>>>(deg, part, row_start, N_NODES);
    int sc_threads = N_EDGES / 4;                              // 400000, exact
    scatter_kernel<<<(sc_threads + 255) / 256, 256, 0, stream>>>(srcp, dstp, rank, row_start,
                                                                 degR, csr, dinv, N_EDGES);

    int n2 = N_NODES * D / 2;
    init_kernel<<<(n2 + 255) / 256, 256, 0, stream>>>((const float2*)node_emb, xb0,
                                                      (float2*)hbuf, n2);

    unsigned int* cur = xb0;
    unsigned int* nxt = xb1;
    for (int k = 0; k < K_HOPS; ++k) {
        agg_kernel<<<(N_NODES + 3) / 4, 256, 0, stream>>>(cur, nxt, (float2*)hbuf,
                                                          selfw, row_start, csr, k & 1);
        unsigned int* tmp = cur; cur = nxt; nxt = tmp;
    }

    // Out-of-place GEMM: reads hbuf (f32), writes d_out.
    dim3 ggrid((N_NODES + 63) / 64, 2);
    gemm_kernel<<<ggrid, 256, 0, stream>>>(hbuf, weight, bias, out);
}